// Round 5
// baseline (184.175 us; speedup 1.0000x reference)
//
#include <hip/hip_runtime.h>
#include <hip/hip_bf16.h>

// ATTRIBUTION ROUND: identical kernels to R4, but k1 is launched 3x (idempotent).
// Delta vs R4 total = 2 * k1_warm. No other changes, no confounds.
//
// SupervisedGraphSage forward via linearity of matmul-over-concat:
//   PQ[i][0:32]  = feat[i] @ W1[:, 0:512].T      (P)
//   PQ[i][32:64] = feat[i] @ W1[:, 512:1024].T   (Q)
//   H1[i] = relu(P[i] + 0.2 * sum_s Q[neigh1[i][s]])
//   comb2[b] = [H1[nodes[b]], 0.2 * sum_s H1[neigh2[b][s]]]
//   out[b] = relu(comb2 @ W2.T) @ Wc.T

#define NFEAT 512
#define NPQ   64
#define HID   32
#define NCLS  40
#define SAMP  5
#define KSTEPS (NFEAT / 16)   // 32

typedef float    f32x4 __attribute__((ext_vector_type(4)));
typedef _Float16 f16x4 __attribute__((ext_vector_type(4)));
typedef _Float16 f16x8 __attribute__((ext_vector_type(8)));

// ---------------- k0: pack W1 (f32 [32][1024]) into f16 B-fragments ----------------
__global__ __launch_bounds__(256) void k0_bfrag(const float* __restrict__ W1,
                                                _Float16* __restrict__ Bfrag) {
  int idx = blockIdx.x * 256 + threadIdx.x;   // (kstep*64 + lane)*4 + tile
  if (idx >= KSTEPS * 64 * 4) return;
  int tile  = idx & 3;
  int lane  = (idx >> 2) & 63;
  int kstep = idx >> 8;
  int n = tile * 16 + (lane & 15);
  int kbase = kstep * 16 + ((lane >> 4) << 2);
  const float* src = W1 + (size_t)(n & 31) * (2 * NFEAT) + (n >> 5) * NFEAT + kbase;
  _Float16* dst = Bfrag + (size_t)idx * 4;
#pragma unroll
  for (int j = 0; j < 4; ++j) dst[j] = (_Float16)src[j];
}

// ---------------- K1: PQ(f16) = feat @ Wr.T via MFMA ----------------
__global__ __launch_bounds__(256) void k1_mfma(
    const float* __restrict__ feat, const _Float16* __restrict__ Bfrag,
    _Float16* __restrict__ PQ, int M) {
  __shared__ _Float16 sC[128][64];

  const int tid  = threadIdx.x;
  const int wave = tid >> 6;
  const int lane = tid & 63;
  const int g    = lane >> 4;
  const int r    = lane & 15;
  const int blockRow = blockIdx.x * 128;
  const int rowbase  = blockRow + wave * 32;

  int arow0 = rowbase + r;
  int arow1 = rowbase + 16 + r;
  if (arow0 >= M) arow0 = M - 1;
  if (arow1 >= M) arow1 = M - 1;
  const float* ap0 = feat + (size_t)arow0 * NFEAT + (g << 2);
  const float* ap1 = feat + (size_t)arow1 * NFEAT + (g << 2);
  const _Float16* bp = Bfrag + (size_t)lane * 16;

  f32x4 acc00 = {0.f,0.f,0.f,0.f}, acc01 = {0.f,0.f,0.f,0.f};
  f32x4 acc02 = {0.f,0.f,0.f,0.f}, acc03 = {0.f,0.f,0.f,0.f};
  f32x4 acc10 = {0.f,0.f,0.f,0.f}, acc11 = {0.f,0.f,0.f,0.f};
  f32x4 acc12 = {0.f,0.f,0.f,0.f}, acc13 = {0.f,0.f,0.f,0.f};

#pragma unroll 4
  for (int ks = 0; ks < KSTEPS; ++ks) {
    float4 av0 = *(const float4*)(ap0 + ks * 16);
    float4 av1 = *(const float4*)(ap1 + ks * 16);
    f16x4 a0, a1;
    a0[0] = (_Float16)av0.x; a0[1] = (_Float16)av0.y;
    a0[2] = (_Float16)av0.z; a0[3] = (_Float16)av0.w;
    a1[0] = (_Float16)av1.x; a1[1] = (_Float16)av1.y;
    a1[2] = (_Float16)av1.z; a1[3] = (_Float16)av1.w;
    const _Float16* bb = bp + (size_t)ks * 1024;
    f16x8 b01 = *(const f16x8*)bb;
    f16x8 b23 = *(const f16x8*)(bb + 8);
    f16x4 b0 = __builtin_shufflevector(b01, b01, 0, 1, 2, 3);
    f16x4 b1 = __builtin_shufflevector(b01, b01, 4, 5, 6, 7);
    f16x4 b2 = __builtin_shufflevector(b23, b23, 0, 1, 2, 3);
    f16x4 b3 = __builtin_shufflevector(b23, b23, 4, 5, 6, 7);
    acc00 = __builtin_amdgcn_mfma_f32_16x16x16f16(a0, b0, acc00, 0, 0, 0);
    acc01 = __builtin_amdgcn_mfma_f32_16x16x16f16(a0, b1, acc01, 0, 0, 0);
    acc02 = __builtin_amdgcn_mfma_f32_16x16x16f16(a0, b2, acc02, 0, 0, 0);
    acc03 = __builtin_amdgcn_mfma_f32_16x16x16f16(a0, b3, acc03, 0, 0, 0);
    acc10 = __builtin_amdgcn_mfma_f32_16x16x16f16(a1, b0, acc10, 0, 0, 0);
    acc11 = __builtin_amdgcn_mfma_f32_16x16x16f16(a1, b1, acc11, 0, 0, 0);
    acc12 = __builtin_amdgcn_mfma_f32_16x16x16f16(a1, b2, acc12, 0, 0, 0);
    acc13 = __builtin_amdgcn_mfma_f32_16x16x16f16(a1, b3, acc13, 0, 0, 0);
  }

  const int lr0 = wave * 32 + 4 * g;
#pragma unroll
  for (int rg = 0; rg < 4; ++rg) {
    sC[lr0 + rg     ][r     ] = (_Float16)acc00[rg];
    sC[lr0 + rg     ][r + 16] = (_Float16)acc01[rg];
    sC[lr0 + rg     ][r + 32] = (_Float16)acc02[rg];
    sC[lr0 + rg     ][r + 48] = (_Float16)acc03[rg];
    sC[lr0 + rg + 16][r     ] = (_Float16)acc10[rg];
    sC[lr0 + rg + 16][r + 16] = (_Float16)acc11[rg];
    sC[lr0 + rg + 16][r + 32] = (_Float16)acc12[rg];
    sC[lr0 + rg + 16][r + 48] = (_Float16)acc13[rg];
  }
  __syncthreads();

  const int srow = tid >> 1;
  const int half = (tid & 1) * 32;
  const int grow = blockRow + srow;
  if (grow < M) {
    _Float16* dst = PQ + (size_t)grow * NPQ + half;
    const _Float16* src = &sC[srow][half];
#pragma unroll
    for (int i = 0; i < 4; ++i)
      *(f16x8*)(dst + i * 8) = *(const f16x8*)(src + i * 8);
  }
}

// ---------------- K2: H1[i] = relu(P[i] + 0.2 * sum_s Q[neigh1[i][s]]) ----------------
__global__ __launch_bounds__(256) void k2_agg(
    const _Float16* __restrict__ PQ, const int* __restrict__ neigh1,
    _Float16* __restrict__ H1, int M) {
  int gid = blockIdx.x * 256 + threadIdx.x;
  if (gid >= M * 4) return;
  int i = gid >> 2;
  int q = gid & 3;

  f16x8 p = *(const f16x8*)(PQ + (size_t)i * NPQ + q * 8);
  float acc[8];
#pragma unroll
  for (int j = 0; j < 8; ++j) acc[j] = 0.f;
#pragma unroll
  for (int s = 0; s < SAMP; ++s) {
    int n = neigh1[i * SAMP + s];
    f16x8 v = *(const f16x8*)(PQ + (size_t)n * NPQ + HID + q * 8);
#pragma unroll
    for (int j = 0; j < 8; ++j) acc[j] += (float)v[j];
  }
  f16x8 rr;
#pragma unroll
  for (int j = 0; j < 8; ++j)
    rr[j] = (_Float16)fmaxf((float)p[j] + 0.2f * acc[j], 0.f);
  *(f16x8*)(H1 + (size_t)i * HID + q * 8) = rr;
}

// ---------------- K3: layer-2 + classifier, one thread per batch row ----------------
__global__ __launch_bounds__(64) void k3_layer2(
    const _Float16* __restrict__ H1, const float* __restrict__ W2,
    const float* __restrict__ Wc, const int* __restrict__ nodes,
    const int* __restrict__ neigh2, float* __restrict__ out, int B) {
  int b = blockIdx.x * 64 + threadIdx.x;
  if (b >= B) return;

  float comb[64];
  {
    const _Float16* hs = H1 + (size_t)nodes[b] * HID;
#pragma unroll
    for (int q = 0; q < 4; ++q) {
      f16x8 v = *(const f16x8*)(hs + q * 8);
#pragma unroll
      for (int j = 0; j < 8; ++j) comb[q * 8 + j] = (float)v[j];
    }
  }
  {
    float na[HID];
#pragma unroll
    for (int h = 0; h < HID; ++h) na[h] = 0.f;
#pragma unroll
    for (int s = 0; s < SAMP; ++s) {
      const _Float16* hn = H1 + (size_t)neigh2[b * SAMP + s] * HID;
#pragma unroll
      for (int q = 0; q < 4; ++q) {
        f16x8 v = *(const f16x8*)(hn + q * 8);
#pragma unroll
        for (int j = 0; j < 8; ++j) na[q * 8 + j] += (float)v[j];
      }
    }
#pragma unroll
    for (int h = 0; h < HID; ++h) comb[HID + h] = 0.2f * na[h];
  }

  float h2[HID];
#pragma unroll 4
  for (int h = 0; h < HID; ++h) {
    float a = 0.f;
#pragma unroll
    for (int k = 0; k < 2 * HID; ++k) a += comb[k] * W2[h * 2 * HID + k];
    h2[h] = a > 0.f ? a : 0.f;
  }

  float* ob = out + (size_t)b * NCLS;
#pragma unroll 4
  for (int c = 0; c < NCLS; ++c) {
    float a = 0.f;
#pragma unroll
    for (int k = 0; k < HID; ++k) a += h2[k] * Wc[c * HID + k];
    ob[c] = a;
  }
}

extern "C" void kernel_launch(void* const* d_in, const int* in_sizes, int n_in,
                              void* d_out, int out_size, void* d_ws, size_t ws_size,
                              hipStream_t stream) {
  const float* feat   = (const float*)d_in[0];
  const float* W1     = (const float*)d_in[1];
  const float* W2     = (const float*)d_in[2];
  const float* Wc     = (const float*)d_in[3];
  const int*   nodes  = (const int*)d_in[4];
  const int*   neigh1 = (const int*)d_in[5];
  const int*   neigh2 = (const int*)d_in[6];
  float* out = (float*)d_out;

  const int M = in_sizes[0] / NFEAT;   // 100000 nodes
  const int B = in_sizes[4];           // 16384 batch

  size_t bfrag_elems = (size_t)KSTEPS * 64 * 4 * 4;
  size_t need = (bfrag_elems + (size_t)M * NPQ + (size_t)M * HID) * sizeof(_Float16);
  if (ws_size < need) return;

  _Float16* Bfrag = (_Float16*)d_ws;
  _Float16* PQ = Bfrag + bfrag_elems;
  _Float16* H1 = PQ + (size_t)M * NPQ;

  k0_bfrag<<<(KSTEPS * 64 * 4 + 255) / 256, 256, 0, stream>>>(W1, Bfrag);
  // k1 launched 3x (idempotent): total delta vs R4 = 2 * k1_warm.
  k1_mfma<<<(M + 127) / 128, 256, 0, stream>>>(feat, Bfrag, PQ, M);
  k1_mfma<<<(M + 127) / 128, 256, 0, stream>>>(feat, Bfrag, PQ, M);
  k1_mfma<<<(M + 127) / 128, 256, 0, stream>>>(feat, Bfrag, PQ, M);
  k2_agg<<<(M * 4 + 255) / 256, 256, 0, stream>>>(PQ, neigh1, H1, M);
  k3_layer2<<<(B + 63) / 64, 64, 0, stream>>>(H1, W2, Wc, nodes, neigh2, out, B);
}

// Round 6
// 161.309 us; speedup vs baseline: 1.1418x; 1.1418x over previous
//
#include <hip/hip_runtime.h>
#include <hip/hip_bf16.h>

// ATTRIBUTION ROUND 2: identical kernels to R4, k1 x1, k2 x3, k3 x3 (all idempotent).
// T = R4_total + 2*(k2+k3). Combined with R5 (k1_warm=42.7us) this fully
// decomposes the pipeline: k0+boundaries = R4_total - k1 - k2 - k3.
//
// SupervisedGraphSage forward via linearity of matmul-over-concat:
//   PQ[i][0:32]  = feat[i] @ W1[:, 0:512].T      (P)
//   PQ[i][32:64] = feat[i] @ W1[:, 512:1024].T   (Q)
//   H1[i] = relu(P[i] + 0.2 * sum_s Q[neigh1[i][s]])
//   comb2[b] = [H1[nodes[b]], 0.2 * sum_s H1[neigh2[b][s]]]
//   out[b] = relu(comb2 @ W2.T) @ Wc.T

#define NFEAT 512
#define NPQ   64
#define HID   32
#define NCLS  40
#define SAMP  5
#define KSTEPS (NFEAT / 16)   // 32

typedef float    f32x4 __attribute__((ext_vector_type(4)));
typedef _Float16 f16x4 __attribute__((ext_vector_type(4)));
typedef _Float16 f16x8 __attribute__((ext_vector_type(8)));

// ---------------- k0: pack W1 (f32 [32][1024]) into f16 B-fragments ----------------
__global__ __launch_bounds__(256) void k0_bfrag(const float* __restrict__ W1,
                                                _Float16* __restrict__ Bfrag) {
  int idx = blockIdx.x * 256 + threadIdx.x;   // (kstep*64 + lane)*4 + tile
  if (idx >= KSTEPS * 64 * 4) return;
  int tile  = idx & 3;
  int lane  = (idx >> 2) & 63;
  int kstep = idx >> 8;
  int n = tile * 16 + (lane & 15);
  int kbase = kstep * 16 + ((lane >> 4) << 2);
  const float* src = W1 + (size_t)(n & 31) * (2 * NFEAT) + (n >> 5) * NFEAT + kbase;
  _Float16* dst = Bfrag + (size_t)idx * 4;
#pragma unroll
  for (int j = 0; j < 4; ++j) dst[j] = (_Float16)src[j];
}

// ---------------- K1: PQ(f16) = feat @ Wr.T via MFMA ----------------
__global__ __launch_bounds__(256) void k1_mfma(
    const float* __restrict__ feat, const _Float16* __restrict__ Bfrag,
    _Float16* __restrict__ PQ, int M) {
  __shared__ _Float16 sC[128][64];

  const int tid  = threadIdx.x;
  const int wave = tid >> 6;
  const int lane = tid & 63;
  const int g    = lane >> 4;
  const int r    = lane & 15;
  const int blockRow = blockIdx.x * 128;
  const int rowbase  = blockRow + wave * 32;

  int arow0 = rowbase + r;
  int arow1 = rowbase + 16 + r;
  if (arow0 >= M) arow0 = M - 1;
  if (arow1 >= M) arow1 = M - 1;
  const float* ap0 = feat + (size_t)arow0 * NFEAT + (g << 2);
  const float* ap1 = feat + (size_t)arow1 * NFEAT + (g << 2);
  const _Float16* bp = Bfrag + (size_t)lane * 16;

  f32x4 acc00 = {0.f,0.f,0.f,0.f}, acc01 = {0.f,0.f,0.f,0.f};
  f32x4 acc02 = {0.f,0.f,0.f,0.f}, acc03 = {0.f,0.f,0.f,0.f};
  f32x4 acc10 = {0.f,0.f,0.f,0.f}, acc11 = {0.f,0.f,0.f,0.f};
  f32x4 acc12 = {0.f,0.f,0.f,0.f}, acc13 = {0.f,0.f,0.f,0.f};

#pragma unroll 4
  for (int ks = 0; ks < KSTEPS; ++ks) {
    float4 av0 = *(const float4*)(ap0 + ks * 16);
    float4 av1 = *(const float4*)(ap1 + ks * 16);
    f16x4 a0, a1;
    a0[0] = (_Float16)av0.x; a0[1] = (_Float16)av0.y;
    a0[2] = (_Float16)av0.z; a0[3] = (_Float16)av0.w;
    a1[0] = (_Float16)av1.x; a1[1] = (_Float16)av1.y;
    a1[2] = (_Float16)av1.z; a1[3] = (_Float16)av1.w;
    const _Float16* bb = bp + (size_t)ks * 1024;
    f16x8 b01 = *(const f16x8*)bb;
    f16x8 b23 = *(const f16x8*)(bb + 8);
    f16x4 b0 = __builtin_shufflevector(b01, b01, 0, 1, 2, 3);
    f16x4 b1 = __builtin_shufflevector(b01, b01, 4, 5, 6, 7);
    f16x4 b2 = __builtin_shufflevector(b23, b23, 0, 1, 2, 3);
    f16x4 b3 = __builtin_shufflevector(b23, b23, 4, 5, 6, 7);
    acc00 = __builtin_amdgcn_mfma_f32_16x16x16f16(a0, b0, acc00, 0, 0, 0);
    acc01 = __builtin_amdgcn_mfma_f32_16x16x16f16(a0, b1, acc01, 0, 0, 0);
    acc02 = __builtin_amdgcn_mfma_f32_16x16x16f16(a0, b2, acc02, 0, 0, 0);
    acc03 = __builtin_amdgcn_mfma_f32_16x16x16f16(a0, b3, acc03, 0, 0, 0);
    acc10 = __builtin_amdgcn_mfma_f32_16x16x16f16(a1, b0, acc10, 0, 0, 0);
    acc11 = __builtin_amdgcn_mfma_f32_16x16x16f16(a1, b1, acc11, 0, 0, 0);
    acc12 = __builtin_amdgcn_mfma_f32_16x16x16f16(a1, b2, acc12, 0, 0, 0);
    acc13 = __builtin_amdgcn_mfma_f32_16x16x16f16(a1, b3, acc13, 0, 0, 0);
  }

  const int lr0 = wave * 32 + 4 * g;
#pragma unroll
  for (int rg = 0; rg < 4; ++rg) {
    sC[lr0 + rg     ][r     ] = (_Float16)acc00[rg];
    sC[lr0 + rg     ][r + 16] = (_Float16)acc01[rg];
    sC[lr0 + rg     ][r + 32] = (_Float16)acc02[rg];
    sC[lr0 + rg     ][r + 48] = (_Float16)acc03[rg];
    sC[lr0 + rg + 16][r     ] = (_Float16)acc10[rg];
    sC[lr0 + rg + 16][r + 16] = (_Float16)acc11[rg];
    sC[lr0 + rg + 16][r + 32] = (_Float16)acc12[rg];
    sC[lr0 + rg + 16][r + 48] = (_Float16)acc13[rg];
  }
  __syncthreads();

  const int srow = tid >> 1;
  const int half = (tid & 1) * 32;
  const int grow = blockRow + srow;
  if (grow < M) {
    _Float16* dst = PQ + (size_t)grow * NPQ + half;
    const _Float16* src = &sC[srow][half];
#pragma unroll
    for (int i = 0; i < 4; ++i)
      *(f16x8*)(dst + i * 8) = *(const f16x8*)(src + i * 8);
  }
}

// ---------------- K2: H1[i] = relu(P[i] + 0.2 * sum_s Q[neigh1[i][s]]) ----------------
__global__ __launch_bounds__(256) void k2_agg(
    const _Float16* __restrict__ PQ, const int* __restrict__ neigh1,
    _Float16* __restrict__ H1, int M) {
  int gid = blockIdx.x * 256 + threadIdx.x;
  if (gid >= M * 4) return;
  int i = gid >> 2;
  int q = gid & 3;

  f16x8 p = *(const f16x8*)(PQ + (size_t)i * NPQ + q * 8);
  float acc[8];
#pragma unroll
  for (int j = 0; j < 8; ++j) acc[j] = 0.f;
#pragma unroll
  for (int s = 0; s < SAMP; ++s) {
    int n = neigh1[i * SAMP + s];
    f16x8 v = *(const f16x8*)(PQ + (size_t)n * NPQ + HID + q * 8);
#pragma unroll
    for (int j = 0; j < 8; ++j) acc[j] += (float)v[j];
  }
  f16x8 rr;
#pragma unroll
  for (int j = 0; j < 8; ++j)
    rr[j] = (_Float16)fmaxf((float)p[j] + 0.2f * acc[j], 0.f);
  *(f16x8*)(H1 + (size_t)i * HID + q * 8) = rr;
}

// ---------------- K3: layer-2 + classifier, one thread per batch row ----------------
__global__ __launch_bounds__(64) void k3_layer2(
    const _Float16* __restrict__ H1, const float* __restrict__ W2,
    const float* __restrict__ Wc, const int* __restrict__ nodes,
    const int* __restrict__ neigh2, float* __restrict__ out, int B) {
  int b = blockIdx.x * 64 + threadIdx.x;
  if (b >= B) return;

  float comb[64];
  {
    const _Float16* hs = H1 + (size_t)nodes[b] * HID;
#pragma unroll
    for (int q = 0; q < 4; ++q) {
      f16x8 v = *(const f16x8*)(hs + q * 8);
#pragma unroll
      for (int j = 0; j < 8; ++j) comb[q * 8 + j] = (float)v[j];
    }
  }
  {
    float na[HID];
#pragma unroll
    for (int h = 0; h < HID; ++h) na[h] = 0.f;
#pragma unroll
    for (int s = 0; s < SAMP; ++s) {
      const _Float16* hn = H1 + (size_t)neigh2[b * SAMP + s] * HID;
#pragma unroll
      for (int q = 0; q < 4; ++q) {
        f16x8 v = *(const f16x8*)(hn + q * 8);
#pragma unroll
        for (int j = 0; j < 8; ++j) na[q * 8 + j] += (float)v[j];
      }
    }
#pragma unroll
    for (int h = 0; h < HID; ++h) comb[HID + h] = 0.2f * na[h];
  }

  float h2[HID];
#pragma unroll 4
  for (int h = 0; h < HID; ++h) {
    float a = 0.f;
#pragma unroll
    for (int k = 0; k < 2 * HID; ++k) a += comb[k] * W2[h * 2 * HID + k];
    h2[h] = a > 0.f ? a : 0.f;
  }

  float* ob = out + (size_t)b * NCLS;
#pragma unroll 4
  for (int c = 0; c < NCLS; ++c) {
    float a = 0.f;
#pragma unroll
    for (int k = 0; k < HID; ++k) a += h2[k] * Wc[c * HID + k];
    ob[c] = a;
  }
}

extern "C" void kernel_launch(void* const* d_in, const int* in_sizes, int n_in,
                              void* d_out, int out_size, void* d_ws, size_t ws_size,
                              hipStream_t stream) {
  const float* feat   = (const float*)d_in[0];
  const float* W1     = (const float*)d_in[1];
  const float* W2     = (const float*)d_in[2];
  const float* Wc     = (const float*)d_in[3];
  const int*   nodes  = (const int*)d_in[4];
  const int*   neigh1 = (const int*)d_in[5];
  const int*   neigh2 = (const int*)d_in[6];
  float* out = (float*)d_out;

  const int M = in_sizes[0] / NFEAT;   // 100000 nodes
  const int B = in_sizes[4];           // 16384 batch

  size_t bfrag_elems = (size_t)KSTEPS * 64 * 4 * 4;
  size_t need = (bfrag_elems + (size_t)M * NPQ + (size_t)M * HID) * sizeof(_Float16);
  if (ws_size < need) return;

  _Float16* Bfrag = (_Float16*)d_ws;
  _Float16* PQ = Bfrag + bfrag_elems;
  _Float16* H1 = PQ + (size_t)M * NPQ;

  k0_bfrag<<<(KSTEPS * 64 * 4 + 255) / 256, 256, 0, stream>>>(W1, Bfrag);
  k1_mfma<<<(M + 127) / 128, 256, 0, stream>>>(feat, Bfrag, PQ, M);
  // k2 and k3 launched 3x each (idempotent): T = R4_total + 2*(k2+k3).
  k2_agg<<<(M * 4 + 255) / 256, 256, 0, stream>>>(PQ, neigh1, H1, M);
  k2_agg<<<(M * 4 + 255) / 256, 256, 0, stream>>>(PQ, neigh1, H1, M);
  k2_agg<<<(M * 4 + 255) / 256, 256, 0, stream>>>(PQ, neigh1, H1, M);
  k3_layer2<<<(B + 63) / 64, 64, 0, stream>>>(H1, W2, Wc, nodes, neigh2, out, B);
  k3_layer2<<<(B + 63) / 64, 64, 0, stream>>>(H1, W2, Wc, nodes, neigh2, out, B);
  k3_layer2<<<(B + 63) / 64, 64, 0, stream>>>(H1, W2, Wc, nodes, neigh2, out, B);
}

// Round 8
// 102.815 us; speedup vs baseline: 1.7913x; 1.5689x over previous
//
#include <hip/hip_runtime.h>
#include <hip/hip_bf16.h>

// SupervisedGraphSage forward via linearity of matmul-over-concat:
//   PQ[i][0:32]  = feat[i] @ W1[:, 0:512].T      (P)
//   PQ[i][32:64] = feat[i] @ W1[:, 512:1024].T   (Q)
//   H1[i] = relu(P[i] + 0.2 * sum_s Q[neigh1[i][s]])
//   comb2[b] = [H1[nodes[b]], 0.2 * sum_s H1[neigh2[b][s]]]
//   out[b] = relu(comb2 @ W2.T) @ Wc.T
//
// R7->R8: k0 folded into k1 (per-block W1->f16 pack into LDS; W1 is 128KB,
// L2-hot). Removes the k0 dispatch + one dependent kernel boundary and halves
// k1's global VMEM instructions. Coop-launch attempt (R7) failed silently --
// abandoned for now.
// Attribution so far: k1=42.7us(incl launch), k2+k3+2 gaps=31.3us,
// k0+gaps+ramp=24.7us.

#define NFEAT 512
#define NPQ   64
#define HID   32
#define NCLS  40
#define SAMP  5
#define KSTEPS (NFEAT / 16)   // 32

typedef float    f32x4 __attribute__((ext_vector_type(4)));
typedef _Float16 f16x4 __attribute__((ext_vector_type(4)));
typedef _Float16 f16x8 __attribute__((ext_vector_type(8)));

// ---------------- K1: PQ(f16) = feat @ Wr.T via MFMA, W1 packed in-block ----------------
// 256 threads = 4 waves; each wave computes 32 rows x 64 cols. Block = 128 rows.
// LDS: B01/B23 fragment tables (64KB, conflict-free lane*16B pattern) + sC (16KB).
__global__ __launch_bounds__(256, 2) void k1_mfma(
    const float* __restrict__ feat, const float* __restrict__ W1,
    _Float16* __restrict__ PQ, int M) {
  __shared__ f16x8 B01[KSTEPS][64];   // tiles 0,1: b0[0..3],b1[0..3]
  __shared__ f16x8 B23[KSTEPS][64];   // tiles 2,3: b2[0..3],b3[0..3]
  __shared__ _Float16 sC[128][64];    // coalesced-store staging

  const int tid  = threadIdx.x;
  const int wave = tid >> 6;
  const int lane = tid & 63;
  const int g    = lane >> 4;
  const int r    = lane & 15;
  const int blockRow = blockIdx.x * 128;
  const int rowbase  = blockRow + wave * 32;

  // ---- pack W1 (f32 [32][1024]) -> LDS f16 fragments ----
  // entry (ks, lane2, half): B[k][n] = W1[n&31][(n>>5)*512 + k],
  //   k = ks*16 + 4*(lane2>>4)+j, n = tile*16 + (lane2&15), tiles {2h, 2h+1}
#pragma unroll
  for (int e = 0; e < 16; ++e) {
    int idx   = e * 256 + tid;        // 4096 entries total
    int half  = idx & 1;
    int lane2 = (idx >> 1) & 63;
    int ks    = idx >> 7;
    int r2    = lane2 & 15;
    int kbase = ks * 16 + ((lane2 >> 4) << 2);
    int n0 = half * 32 + r2;          // tile 2*half
    int n1 = n0 + 16;                 // tile 2*half+1
    const float4 fa = *(const float4*)(W1 + (size_t)(n0 & 31) * (2 * NFEAT) + (n0 >> 5) * NFEAT + kbase);
    const float4 fb = *(const float4*)(W1 + (size_t)(n1 & 31) * (2 * NFEAT) + (n1 >> 5) * NFEAT + kbase);
    f16x8 v;
    v[0] = (_Float16)fa.x; v[1] = (_Float16)fa.y;
    v[2] = (_Float16)fa.z; v[3] = (_Float16)fa.w;
    v[4] = (_Float16)fb.x; v[5] = (_Float16)fb.y;
    v[6] = (_Float16)fb.z; v[7] = (_Float16)fb.w;
    if (half) B23[ks][lane2] = v; else B01[ks][lane2] = v;
  }
  __syncthreads();

  int arow0 = rowbase + r;
  int arow1 = rowbase + 16 + r;
  if (arow0 >= M) arow0 = M - 1;     // clamp; stores guarded
  if (arow1 >= M) arow1 = M - 1;
  const float* ap0 = feat + (size_t)arow0 * NFEAT + (g << 2);
  const float* ap1 = feat + (size_t)arow1 * NFEAT + (g << 2);

  f32x4 acc00 = {0.f,0.f,0.f,0.f}, acc01 = {0.f,0.f,0.f,0.f};
  f32x4 acc02 = {0.f,0.f,0.f,0.f}, acc03 = {0.f,0.f,0.f,0.f};
  f32x4 acc10 = {0.f,0.f,0.f,0.f}, acc11 = {0.f,0.f,0.f,0.f};
  f32x4 acc12 = {0.f,0.f,0.f,0.f}, acc13 = {0.f,0.f,0.f,0.f};

#pragma unroll 4
  for (int ks = 0; ks < KSTEPS; ++ks) {
    float4 av0 = *(const float4*)(ap0 + ks * 16);
    float4 av1 = *(const float4*)(ap1 + ks * 16);
    f16x4 a0, a1;
    a0[0] = (_Float16)av0.x; a0[1] = (_Float16)av0.y;
    a0[2] = (_Float16)av0.z; a0[3] = (_Float16)av0.w;
    a1[0] = (_Float16)av1.x; a1[1] = (_Float16)av1.y;
    a1[2] = (_Float16)av1.z; a1[3] = (_Float16)av1.w;
    f16x8 b01 = B01[ks][lane];
    f16x8 b23 = B23[ks][lane];
    f16x4 b0 = __builtin_shufflevector(b01, b01, 0, 1, 2, 3);
    f16x4 b1 = __builtin_shufflevector(b01, b01, 4, 5, 6, 7);
    f16x4 b2 = __builtin_shufflevector(b23, b23, 0, 1, 2, 3);
    f16x4 b3 = __builtin_shufflevector(b23, b23, 4, 5, 6, 7);
    acc00 = __builtin_amdgcn_mfma_f32_16x16x16f16(a0, b0, acc00, 0, 0, 0);
    acc01 = __builtin_amdgcn_mfma_f32_16x16x16f16(a0, b1, acc01, 0, 0, 0);
    acc02 = __builtin_amdgcn_mfma_f32_16x16x16f16(a0, b2, acc02, 0, 0, 0);
    acc03 = __builtin_amdgcn_mfma_f32_16x16x16f16(a0, b3, acc03, 0, 0, 0);
    acc10 = __builtin_amdgcn_mfma_f32_16x16x16f16(a1, b0, acc10, 0, 0, 0);
    acc11 = __builtin_amdgcn_mfma_f32_16x16x16f16(a1, b1, acc11, 0, 0, 0);
    acc12 = __builtin_amdgcn_mfma_f32_16x16x16f16(a1, b2, acc12, 0, 0, 0);
    acc13 = __builtin_amdgcn_mfma_f32_16x16x16f16(a1, b3, acc13, 0, 0, 0);
  }

  // C layout per tile: row = 4g + reg (+ rt*16), col = t*16 + r.
  const int lr0 = wave * 32 + 4 * g;
#pragma unroll
  for (int rg = 0; rg < 4; ++rg) {
    sC[lr0 + rg     ][r     ] = (_Float16)acc00[rg];
    sC[lr0 + rg     ][r + 16] = (_Float16)acc01[rg];
    sC[lr0 + rg     ][r + 32] = (_Float16)acc02[rg];
    sC[lr0 + rg     ][r + 48] = (_Float16)acc03[rg];
    sC[lr0 + rg + 16][r     ] = (_Float16)acc10[rg];
    sC[lr0 + rg + 16][r + 16] = (_Float16)acc11[rg];
    sC[lr0 + rg + 16][r + 32] = (_Float16)acc12[rg];
    sC[lr0 + rg + 16][r + 48] = (_Float16)acc13[rg];
  }
  __syncthreads();

  const int srow = tid >> 1;
  const int half = (tid & 1) * 32;
  const int grow = blockRow + srow;
  if (grow < M) {
    _Float16* dst = PQ + (size_t)grow * NPQ + half;
    const _Float16* srcp = &sC[srow][half];
#pragma unroll
    for (int i = 0; i < 4; ++i)
      *(f16x8*)(dst + i * 8) = *(const f16x8*)(srcp + i * 8);
  }
}

// ---------------- K2: H1[i] = relu(P[i] + 0.2 * sum_s Q[neigh1[i][s]]) ----------------
__global__ __launch_bounds__(256) void k2_agg(
    const _Float16* __restrict__ PQ, const int* __restrict__ neigh1,
    _Float16* __restrict__ H1, int M) {
  int gid = blockIdx.x * 256 + threadIdx.x;
  if (gid >= M * 4) return;
  int i = gid >> 2;
  int q = gid & 3;

  f16x8 p = *(const f16x8*)(PQ + (size_t)i * NPQ + q * 8);
  float acc[8];
#pragma unroll
  for (int j = 0; j < 8; ++j) acc[j] = 0.f;
#pragma unroll
  for (int s = 0; s < SAMP; ++s) {
    int n = neigh1[i * SAMP + s];
    f16x8 v = *(const f16x8*)(PQ + (size_t)n * NPQ + HID + q * 8);
#pragma unroll
    for (int j = 0; j < 8; ++j) acc[j] += (float)v[j];
  }
  f16x8 rr;
#pragma unroll
  for (int j = 0; j < 8; ++j)
    rr[j] = (_Float16)fmaxf((float)p[j] + 0.2f * acc[j], 0.f);
  *(f16x8*)(H1 + (size_t)i * HID + q * 8) = rr;
}

// ---------------- K3: layer-2 + classifier, one thread per batch row ----------------
__global__ __launch_bounds__(64) void k3_layer2(
    const _Float16* __restrict__ H1, const float* __restrict__ W2,
    const float* __restrict__ Wc, const int* __restrict__ nodes,
    const int* __restrict__ neigh2, float* __restrict__ out, int B) {
  int b = blockIdx.x * 64 + threadIdx.x;
  if (b >= B) return;

  float comb[64];
  {
    const _Float16* hs = H1 + (size_t)nodes[b] * HID;
#pragma unroll
    for (int q = 0; q < 4; ++q) {
      f16x8 v = *(const f16x8*)(hs + q * 8);
#pragma unroll
      for (int j = 0; j < 8; ++j) comb[q * 8 + j] = (float)v[j];
    }
  }
  {
    float na[HID];
#pragma unroll
    for (int h = 0; h < HID; ++h) na[h] = 0.f;
#pragma unroll
    for (int s = 0; s < SAMP; ++s) {
      const _Float16* hn = H1 + (size_t)neigh2[b * SAMP + s] * HID;
#pragma unroll
      for (int q = 0; q < 4; ++q) {
        f16x8 v = *(const f16x8*)(hn + q * 8);
#pragma unroll
        for (int j = 0; j < 8; ++j) na[q * 8 + j] += (float)v[j];
      }
    }
#pragma unroll
    for (int h = 0; h < HID; ++h) comb[HID + h] = 0.2f * na[h];
  }

  float h2[HID];
#pragma unroll 4
  for (int h = 0; h < HID; ++h) {
    float a = 0.f;
#pragma unroll
    for (int k = 0; k < 2 * HID; ++k) a += comb[k] * W2[h * 2 * HID + k];
    h2[h] = a > 0.f ? a : 0.f;
  }

  float* ob = out + (size_t)b * NCLS;
#pragma unroll 4
  for (int c = 0; c < NCLS; ++c) {
    float a = 0.f;
#pragma unroll
    for (int k = 0; k < HID; ++k) a += h2[k] * Wc[c * HID + k];
    ob[c] = a;
  }
}

extern "C" void kernel_launch(void* const* d_in, const int* in_sizes, int n_in,
                              void* d_out, int out_size, void* d_ws, size_t ws_size,
                              hipStream_t stream) {
  const float* feat   = (const float*)d_in[0];
  const float* W1     = (const float*)d_in[1];
  const float* W2     = (const float*)d_in[2];
  const float* Wc     = (const float*)d_in[3];
  const int*   nodes  = (const int*)d_in[4];
  const int*   neigh1 = (const int*)d_in[5];
  const int*   neigh2 = (const int*)d_in[6];
  float* out = (float*)d_out;

  const int M = in_sizes[0] / NFEAT;   // 100000 nodes
  const int B = in_sizes[4];           // 16384 batch

  // workspace: PQ f16 [M][64], H1 f16 [M][32]
  size_t need = ((size_t)M * NPQ + (size_t)M * HID) * sizeof(_Float16);
  if (ws_size < need) return;  // fail loudly (output stays poisoned)

  _Float16* PQ = (_Float16*)d_ws;
  _Float16* H1 = PQ + (size_t)M * NPQ;

  k1_mfma<<<(M + 127) / 128, 256, 0, stream>>>(feat, W1, PQ, M);
  k2_agg<<<(M * 4 + 255) / 256, 256, 0, stream>>>(PQ, neigh1, H1, M);
  k3_layer2<<<(B + 63) / 64, 64, 0, stream>>>(H1, W2, Wc, nodes, neigh2, out, B);
}